// Round 2
// baseline (36.194 us; speedup 1.0000x reference)
//
#include <hip/hip_runtime.h>

#define NUM_ROIS 8192
#define NUM_CLASSES 20
#define FG_THRESH 0.5f
#define BG_HI 0.5f
#define BG_LO 0.1f
#define NBLK (NUM_ROIS / 256)

// Single fused kernel. Every block independently computes the 20 per-class
// argmax seeds from S (640 KB, L2/L3-resident after first touch), then labels
// its own 256 ROIs via a 20-element gather from U.
// out[0:8192]     = RL as float32 (exact small integers)
// out[8192:16384] = RW float32
__global__ __launch_bounds__(256) void roilabel_fused(
    const float* __restrict__ S,
    const float* __restrict__ U,
    const float* __restrict__ L,
    const float* __restrict__ CW,
    float* __restrict__ out) {

    const int t = threadIdx.x;

    // ---- Phase 1: per-class argmax over S[:, c], first-occurrence semantics.
    float bv[NUM_CLASSES];
    int   bi[NUM_CLASSES];
    #pragma unroll
    for (int c = 0; c < NUM_CLASSES; ++c) { bv[c] = -__builtin_inff(); bi[c] = 0; }

    // S viewed as [8192][5] float4 (20 floats per row). Thread t scans rows
    // t, t+256, ... ascending -> strict '>' keeps the lowest row index among
    // equal maxima within this thread. All class indices are compile-time.
    const float4* __restrict__ S4 = (const float4*)S;
    for (int r = t; r < NUM_ROIS; r += 256) {
        #pragma unroll
        for (int j = 0; j < 5; ++j) {
            float4 v = S4[r * 5 + j];
            if (v.x > bv[j * 4 + 0]) { bv[j * 4 + 0] = v.x; bi[j * 4 + 0] = r; }
            if (v.y > bv[j * 4 + 1]) { bv[j * 4 + 1] = v.y; bi[j * 4 + 1] = r; }
            if (v.z > bv[j * 4 + 2]) { bv[j * 4 + 2] = v.z; bi[j * 4 + 2] = r; }
            if (v.w > bv[j * 4 + 3]) { bv[j * 4 + 3] = v.w; bi[j * 4 + 3] = r; }
        }
    }

    __shared__ float sv[NUM_CLASSES][256];
    __shared__ int   si[NUM_CLASSES][256];
    #pragma unroll
    for (int c = 0; c < NUM_CLASSES; ++c) { sv[c][t] = bv[c]; si[c][t] = bi[c]; }
    __syncthreads();

    // Tree reduce across threads; ties toward smaller row index -> global
    // first-occurrence argmax (jnp.argmax axis=0).
    for (int off = 128; off > 0; off >>= 1) {
        if (t < off) {
            #pragma unroll
            for (int c = 0; c < NUM_CLASSES; ++c) {
                float v2 = sv[c][t + off];
                int   i2 = si[c][t + off];
                if (v2 > sv[c][t] || (v2 == sv[c][t] && i2 < si[c][t])) {
                    sv[c][t] = v2;
                    si[c][t] = i2;
                }
            }
        }
        __syncthreads();
    }

    __shared__ int   s_seed[NUM_CLASSES];
    __shared__ int   s_valid[NUM_CLASSES];
    __shared__ float s_cw[NUM_CLASSES];
    if (t < NUM_CLASSES) {
        s_seed[t]  = si[t][0];
        s_valid[t] = (L[t] > 0.0f) ? 1 : 0;
        s_cw[t]    = CW[t];
    }
    __syncthreads();

    // ---- Phase 2: label this block's 256 ROIs.
    const int i = blockIdx.x * 256 + t;
    const float* __restrict__ row = U + (size_t)i * NUM_ROIS;

    float best_iou = -2.0f;  // below the -1.0 "invalid" marker
    int best_c = 0;
    #pragma unroll
    for (int c = 0; c < NUM_CLASSES; ++c) {
        float v = s_valid[c] ? row[s_seed[c]] : -1.0f;
        // strict '>' keeps the FIRST class among equal maxima (argmax axis=1)
        if (v > best_iou) { best_iou = v; best_c = c; }
    }

    const bool is_fg = (best_iou >= FG_THRESH);
    const bool is_bg = (best_iou < BG_HI) && (best_iou >= BG_LO);

    int   rl = is_fg ? (best_c + 1) : (is_bg ? 0 : -1);
    float rw = (is_fg || is_bg) ? s_cw[best_c] : 0.0f;

    out[i]            = (float)rl;
    out[NUM_ROIS + i] = rw;
}

extern "C" void kernel_launch(void* const* d_in, const int* in_sizes, int n_in,
                              void* d_out, int out_size, void* d_ws, size_t ws_size,
                              hipStream_t stream) {
    const float* S  = (const float*)d_in[0];  // [8192, 20]
    const float* U  = (const float*)d_in[1];  // [8192, 8192]
    const float* L  = (const float*)d_in[2];  // [1, 20]
    const float* CW = (const float*)d_in[3];  // [1, 20]
    float* out = (float*)d_out;               // [16384] = RL(8192) ++ RW(8192)

    roilabel_fused<<<NBLK, 256, 0, stream>>>(S, U, L, CW, out);
}

// Round 3
// 21.280 us; speedup vs baseline: 1.7008x; 1.7008x over previous
//
#include <hip/hip_runtime.h>

#define NUM_ROIS 8192
#define NUM_CLASSES 20
#define FG_THRESH 0.5f
#define BG_HI 0.5f
#define BG_LO 0.1f
#define K1_BLOCKS 32          // 256 rows of S per block, 1 row per thread
#define K2_ROIS_PER_BLOCK 8   // 32 lanes per ROI (lane = class slot)

// d_ws layout: unsigned long long keys[NUM_CLASSES][K1_BLOCKS]
// key = (float_bits(v) << 32) | (NUM_ROIS-1-row)
// (S values are non-negative, so float bits are monotone; max key = max value,
//  ties broken toward the smaller row index = jnp.argmax first-occurrence.)

__global__ __launch_bounds__(256) void roilabel_seeds(
    const float* __restrict__ S,
    unsigned long long* __restrict__ keys) {

    const int t   = threadIdx.x;
    const int row = blockIdx.x * 256 + t;

    // One row per thread: 20 consecutive floats = 5 aligned float4 loads.
    const float4* __restrict__ S4 = (const float4*)(S + (size_t)row * NUM_CLASSES);
    float4 r0 = S4[0], r1 = S4[1], r2 = S4[2], r3 = S4[3], r4 = S4[4];
    float v[NUM_CLASSES] = { r0.x, r0.y, r0.z, r0.w,
                             r1.x, r1.y, r1.z, r1.w,
                             r2.x, r2.y, r2.z, r2.w,
                             r3.x, r3.y, r3.z, r3.w,
                             r4.x, r4.y, r4.z, r4.w };

    __shared__ unsigned long long lds[NUM_CLASSES][4];
    const int wave = t >> 6;
    const int lane = t & 63;

    #pragma unroll
    for (int c = 0; c < NUM_CLASSES; ++c) {
        float bv = v[c];
        int   bi = row;
        // 64-lane butterfly; ties toward smaller row index.
        #pragma unroll
        for (int m = 32; m > 0; m >>= 1) {
            float ov = __shfl_xor(bv, m);
            int   oi = __shfl_xor(bi, m);
            if (ov > bv || (ov == bv && oi < bi)) { bv = ov; bi = oi; }
        }
        if (lane == 0)
            lds[c][wave] = ((unsigned long long)__float_as_uint(bv) << 32)
                         | (unsigned)(NUM_ROIS - 1 - bi);
    }
    __syncthreads();

    if (t < NUM_CLASSES) {
        unsigned long long k = lds[t][0];
        #pragma unroll
        for (int w = 1; w < 4; ++w) {
            unsigned long long k2 = lds[t][w];
            if (k2 > k) k = k2;
        }
        keys[t * K1_BLOCKS + blockIdx.x] = k;
    }
}

// One 32-lane group per ROI; lane index = class. 1024 blocks spread the
// scattered U gather across all CUs for latency hiding.
// out[0:8192] = RL as float32 (exact small ints), out[8192:16384] = RW.
__global__ __launch_bounds__(256) void roilabel_assign(
    const float* __restrict__ U,
    const float* __restrict__ L,
    const float* __restrict__ CW,
    const unsigned long long* __restrict__ keys,
    float* __restrict__ out) {

    __shared__ int   s_seed[NUM_CLASSES];
    __shared__ int   s_valid[NUM_CLASSES];
    __shared__ float s_cw[NUM_CLASSES];

    const int t = threadIdx.x;
    if (t < NUM_CLASSES) {
        unsigned long long k = keys[t * K1_BLOCKS];
        #pragma unroll
        for (int b = 1; b < K1_BLOCKS; ++b) {
            unsigned long long k2 = keys[t * K1_BLOCKS + b];
            if (k2 > k) k = k2;
        }
        s_seed[t]  = NUM_ROIS - 1 - (int)(unsigned)(k & 0xFFFFFFFFull);
        s_valid[t] = (L[t] > 0.0f) ? 1 : 0;
        s_cw[t]    = CW[t];
    }
    __syncthreads();

    const int sub = t & 31;                                  // class slot
    const int roi = blockIdx.x * K2_ROIS_PER_BLOCK + (t >> 5);

    float v = -2.0f;   // below the -1.0 "invalid" marker -> idle lanes lose
    int   c = 999;
    if (sub < NUM_CLASSES) {
        c = sub;
        v = s_valid[sub] ? U[(size_t)roi * NUM_ROIS + s_seed[sub]] : -1.0f;
    }
    // 32-lane argmax (masks <32 stay within the 32-group); ties -> smaller c.
    #pragma unroll
    for (int m = 16; m > 0; m >>= 1) {
        float ov = __shfl_xor(v, m);
        int   oc = __shfl_xor(c, m);
        if (ov > v || (ov == v && oc < c)) { v = ov; c = oc; }
    }

    if (sub == 0) {
        const bool fg = (v >= FG_THRESH);
        const bool bg = (v < BG_HI) && (v >= BG_LO);
        out[roi]            = (float)(fg ? c + 1 : (bg ? 0 : -1));
        out[NUM_ROIS + roi] = (fg || bg) ? s_cw[c] : 0.0f;
    }
}

extern "C" void kernel_launch(void* const* d_in, const int* in_sizes, int n_in,
                              void* d_out, int out_size, void* d_ws, size_t ws_size,
                              hipStream_t stream) {
    const float* S  = (const float*)d_in[0];  // [8192, 20]
    const float* U  = (const float*)d_in[1];  // [8192, 8192]
    const float* L  = (const float*)d_in[2];  // [1, 20]
    const float* CW = (const float*)d_in[3];  // [1, 20]
    float* out = (float*)d_out;               // RL(8192) ++ RW(8192)
    unsigned long long* keys = (unsigned long long*)d_ws;  // [20][32]

    roilabel_seeds<<<K1_BLOCKS, 256, 0, stream>>>(S, keys);
    roilabel_assign<<<NUM_ROIS / K2_ROIS_PER_BLOCK, 256, 0, stream>>>(U, L, CW, keys, out);
}